// Round 1
// baseline (84.815 us; speedup 1.0000x reference)
//
#include <hip/hip_runtime.h>
#include <hip/hip_bf16.h>

#define NROWS 8192
#define DIM 256

typedef __bf16 bf16x8 __attribute__((ext_vector_type(8)));
typedef float f32x4 __attribute__((ext_vector_type(4)));

// ---------------- Kernel 1: L2-normalize rows, fp32 -> bf16 ----------------
// One wave per row: 64 lanes x float4 = 256 elements.
__global__ __launch_bounds__(256) void k_normalize(const float* __restrict__ in,
                                                   __hip_bfloat16* __restrict__ out) {
    const int row  = blockIdx.x * 4 + (threadIdx.x >> 6);
    const int lane = threadIdx.x & 63;
    const float4 v = reinterpret_cast<const float4*>(in + (size_t)row * DIM)[lane];
    float ss = v.x * v.x + v.y * v.y + v.z * v.z + v.w * v.w;
#pragma unroll
    for (int m = 32; m >= 1; m >>= 1) ss += __shfl_xor(ss, m, 64);
    const float inv = 1.0f / fmaxf(sqrtf(ss), 1e-8f);
    __hip_bfloat16 o[4];
    o[0] = __float2bfloat16(v.x * inv);
    o[1] = __float2bfloat16(v.y * inv);
    o[2] = __float2bfloat16(v.z * inv);
    o[3] = __float2bfloat16(v.w * inv);
    reinterpret_cast<ushort4*>(out + (size_t)row * DIM)[lane] = *reinterpret_cast<const ushort4*>(o);
}

// ---------------- Kernel 2: fused sim-GEMM + row sum of exp(-s) ----------------
// Grid: 128 i-blocks (BM=64 rows) x NSPLIT j-ranges. Block = 256 thr = 4 waves (2x2).
// Wave (wm,wn): rows i0 = ib*64+wm*32 (+0,+16), cols wn*32 (+0,+16) within a BN=64 j-tile.
#define BM 64
#define BN 64
#define NSPLIT 4
#define JSPAN (NROWS / NSPLIT) /* 2048 */
#define NJT (JSPAN / BN)       /* 32 */

__global__ __launch_bounds__(256) void k_simlse(const __hip_bfloat16* __restrict__ En,
                                                const __hip_bfloat16* __restrict__ Qn,
                                                float* __restrict__ rowsum,
                                                float* __restrict__ pickv) {
    __shared__ char lds[BN * 512];  // 32 KB swizzled Q tile: [col][512B of K]
    const int bx   = blockIdx.x;    // 0..511
    const int ib   = bx >> 2;       // 0..127
    const int jq   = bx & 3;
    const int tid  = threadIdx.x;
    const int lane = tid & 63;
    const int w    = tid >> 6;
    const int wm   = w >> 1;
    const int wn   = w & 1;
    const int l15  = lane & 15;
    const int lks  = lane >> 4;     // k-segment 0..3

    const int i0 = ib * BM + wm * 32;

    // Hoist A fragments (32 rows x K=256) into registers.
    // A-frag layout (16x16x32): row = lane&15, k = (lane>>4)*8 + e  (16B contiguous).
    bf16x8 a[2][8];
    {
        const __hip_bfloat16* ab = En + (size_t)(i0 + l15) * DIM + lks * 8;
#pragma unroll
        for (int mi = 0; mi < 2; ++mi)
#pragma unroll
            for (int kk = 0; kk < 8; ++kk)
                a[mi][kk] = *reinterpret_cast<const bf16x8*>(ab + mi * 16 * DIM + kk * 32);
    }

    float racc[2][4];
#pragma unroll
    for (int mi = 0; mi < 2; ++mi)
#pragma unroll
        for (int r = 0; r < 4; ++r) racc[mi][r] = 0.0f;

    for (int jt = 0; jt < NJT; ++jt) {
        const int jbase = jq * JSPAN + jt * BN;
        __syncthreads();  // previous tile fully consumed
        // Stage Q tile: 2048 chunks of 16B; LDS byte = c*512 + ((seg*16) ^ ((c&7)<<4))
#pragma unroll
        for (int rr = 0; rr < 8; ++rr) {
            const int id  = rr * 256 + tid;
            const int c   = id >> 5;
            const int seg = id & 31;
            const uint4 val = *reinterpret_cast<const uint4*>(
                reinterpret_cast<const char*>(Qn + (size_t)(jbase + c) * DIM) + seg * 16);
            *reinterpret_cast<uint4*>(&lds[c * 512 + ((seg * 16) ^ ((c & 7) << 4))]) = val;
        }
        __syncthreads();

        // B fragments from LDS (col = lane&15, k = (lane>>4)*8 + e)
        bf16x8 b[2][8];
#pragma unroll
        for (int ci = 0; ci < 2; ++ci) {
            const int cl   = wn * 32 + ci * 16 + l15;
            const int base = cl * 512;
            const int swz  = (cl & 7) << 4;
#pragma unroll
            for (int kk = 0; kk < 8; ++kk)
                b[ci][kk] = *reinterpret_cast<const bf16x8*>(
                    &lds[base + ((kk * 64 + lks * 16) ^ swz)]);
        }

        f32x4 acc[2][2];
#pragma unroll
        for (int mi = 0; mi < 2; ++mi)
#pragma unroll
            for (int ci = 0; ci < 2; ++ci) acc[mi][ci] = f32x4{0.f, 0.f, 0.f, 0.f};

#pragma unroll
        for (int kk = 0; kk < 8; ++kk)
#pragma unroll
            for (int mi = 0; mi < 2; ++mi)
#pragma unroll
                for (int ci = 0; ci < 2; ++ci)
                    acc[mi][ci] = __builtin_amdgcn_mfma_f32_16x16x32_bf16(
                        a[mi][kk], b[ci][kk], acc[mi][ci], 0, 0, 0);

        // Epilogue: C/D layout col = lane&15, row = (lane>>4)*4 + r
#pragma unroll
        for (int mi = 0; mi < 2; ++mi) {
            const int ig0 = i0 + mi * 16 + lks * 4;
#pragma unroll
            for (int ci = 0; ci < 2; ++ci) {
                const int jg = jbase + wn * 32 + ci * 16 + l15;
#pragma unroll
                for (int r = 0; r < 4; ++r) {
                    const float s  = acc[mi][ci][r];
                    const int   ig = ig0 + r;
                    racc[mi][r] += (jg == ig) ? 0.0f : __expf(-s);
                    const int pc = (ig == NROWS - 1) ? (NROWS - 2) : (ig + 1);
                    if (jg == pc) pickv[ig] = s;
                }
            }
        }
    }

    // Reduce row partials across the 16 lanes of each k-group, one atomicAdd per row.
#pragma unroll
    for (int mi = 0; mi < 2; ++mi)
#pragma unroll
        for (int r = 0; r < 4; ++r) {
            float v = racc[mi][r];
#pragma unroll
            for (int m = 1; m < 16; m <<= 1) v += __shfl_xor(v, m, 64);
            if (l15 == 0) atomicAdd(&rowsum[i0 + mi * 16 + lks * 4 + r], v);
        }
}

// ---------------- Kernel 3: deterministic final reduce ----------------
__global__ __launch_bounds__(256) void k_finalize(const float* __restrict__ rowsum,
                                                  const float* __restrict__ pickv,
                                                  float* __restrict__ out) {
    __shared__ float red[4];
    float s = 0.0f;
    for (int i = threadIdx.x; i < NROWS; i += 256) s += logf(rowsum[i]) + pickv[i];
#pragma unroll
    for (int m = 32; m >= 1; m >>= 1) s += __shfl_xor(s, m, 64);
    if ((threadIdx.x & 63) == 0) red[threadIdx.x >> 6] = s;
    __syncthreads();
    if (threadIdx.x == 0)
        out[0] = (red[0] + red[1] + red[2] + red[3]) * (1.0f / (float)NROWS);
}

extern "C" void kernel_launch(void* const* d_in, const int* in_sizes, int n_in,
                              void* d_out, int out_size, void* d_ws, size_t ws_size,
                              hipStream_t stream) {
    const float* emb = (const float*)d_in[0];
    const float* qry = (const float*)d_in[1];
    float* out = (float*)d_out;

    char* ws = (char*)d_ws;
    __hip_bfloat16* En = (__hip_bfloat16*)ws;                                  // 4 MB
    __hip_bfloat16* Qn = (__hip_bfloat16*)(ws + (size_t)NROWS * DIM * 2);      // 4 MB
    float* rowsum = (float*)(ws + (size_t)NROWS * DIM * 4);                    // 32 KB
    float* pickv  = rowsum + NROWS;                                            // 32 KB

    hipMemsetAsync(rowsum, 0, NROWS * sizeof(float), stream);
    k_normalize<<<NROWS / 4, 256, 0, stream>>>(emb, En);
    k_normalize<<<NROWS / 4, 256, 0, stream>>>(qry, Qn);
    k_simlse<<<128 * NSPLIT, 256, 0, stream>>>(En, Qn, rowsum, pickv);
    k_finalize<<<1, 256, 0, stream>>>(rowsum, pickv, out);
}

// Round 2
// 73.724 us; speedup vs baseline: 1.1504x; 1.1504x over previous
//
#include <hip/hip_runtime.h>
#include <hip/hip_bf16.h>

#define NROWS 8192
#define DIM 256
#define NSPLIT 16
#define JSPAN (NROWS / NSPLIT)   /* 512 cols per block */
#define BN 64
#define NT (JSPAN / BN)          /* 8 tiles per block */
#define RPW 64                   /* rows per wave (A stationary) */
#define RPB 256                  /* rows per block (4 waves) */

typedef __bf16 bf16x8 __attribute__((ext_vector_type(8)));
typedef float f32x4 __attribute__((ext_vector_type(4)));

// ---------------- Kernel 1: L2-normalize rows, fp32 -> bf16 ----------------
__global__ __launch_bounds__(256) void k_normalize(const float* __restrict__ in,
                                                   __hip_bfloat16* __restrict__ out) {
    const int row  = blockIdx.x * 4 + (threadIdx.x >> 6);
    const int lane = threadIdx.x & 63;
    const float4 v = reinterpret_cast<const float4*>(in + (size_t)row * DIM)[lane];
    float ss = v.x * v.x + v.y * v.y + v.z * v.z + v.w * v.w;
#pragma unroll
    for (int m = 32; m >= 1; m >>= 1) ss += __shfl_xor(ss, m, 64);
    const float inv = 1.0f / fmaxf(sqrtf(ss), 1e-8f);
    __hip_bfloat16 o[4];
    o[0] = __float2bfloat16(v.x * inv);
    o[1] = __float2bfloat16(v.y * inv);
    o[2] = __float2bfloat16(v.z * inv);
    o[3] = __float2bfloat16(v.w * inv);
    reinterpret_cast<ushort4*>(out + (size_t)row * DIM)[lane] = *reinterpret_cast<const ushort4*>(o);
}

// Stage one BN x DIM bf16 tile (32 KB) into LDS via global_load_lds, width 16.
// LDS dest is LINEAR (wave-uniform base + lane*16); the swizzle is applied by
// permuting the SOURCE address (involution: XOR of byte bits 4..6 with col&7),
// so ds_read with the same XOR recovers linear data (both-sides rule, G21).
__device__ __forceinline__ void stage_tile(const char* __restrict__ gbase,
                                           char* lbase, int tid) {
    const int wbase = tid & 192;   // wave-uniform part of tid
    const int lane  = tid & 63;
#pragma unroll
    for (int rr = 0; rr < 8; ++rr) {
        const int id  = rr * 256 + wbase + lane;   // chunk id 0..2047
        const int c   = id >> 5;                   // local col 0..63
        const int off = (id & 31) * 16;            // byte in col's 512B row
        const char* src = gbase + c * 512 + (off ^ ((c & 7) << 4));
        char* dst = lbase + (rr * 256 + wbase) * 16;   // wave-uniform
        __builtin_amdgcn_global_load_lds(
            (const __attribute__((address_space(1))) void*)src,
            (__attribute__((address_space(3))) void*)dst, 16, 0, 0);
    }
}

// ---------------- Kernel 2: fused sim-GEMM + row sum of exp(-s) ----------------
// Grid: 32 i-blocks (256 rows) x 16 j-splits. Block = 256 thr = 4 waves.
// Each wave: 64 stationary A-rows in registers; all waves share the LDS Q-tile.
__global__ __launch_bounds__(256, 2) void k_simlse(const __hip_bfloat16* __restrict__ En,
                                                   const __hip_bfloat16* __restrict__ Qn,
                                                   float* __restrict__ rowsum,
                                                   float* __restrict__ pickv) {
    __shared__ char lds[2][BN * 512];   // 2 x 32 KB double buffer
    const int bx   = blockIdx.x;
    const int ib   = bx >> 4;
    const int jq   = bx & 15;
    const int tid  = threadIdx.x;
    const int lane = tid & 63;
    const int w    = tid >> 6;
    const int l15  = lane & 15;
    const int lks  = lane >> 4;          // k-segment 0..3
    const int i0w  = ib * RPB + w * RPW; // this wave's first row

    // A fragments: 64 rows x K=256 -> a[4][8], 128 VGPRs.
    bf16x8 a[4][8];
    {
        const __hip_bfloat16* ab = En + (size_t)(i0w + l15) * DIM + lks * 8;
#pragma unroll
        for (int mi = 0; mi < 4; ++mi)
#pragma unroll
            for (int kk = 0; kk < 8; ++kk)
                a[mi][kk] = *reinterpret_cast<const bf16x8*>(ab + mi * 16 * DIM + kk * 32);
    }

    float racc[4][4];
#pragma unroll
    for (int mi = 0; mi < 4; ++mi)
#pragma unroll
        for (int r = 0; r < 4; ++r) racc[mi][r] = 0.0f;

    const char* qbase = (const char*)Qn + (size_t)jq * JSPAN * 512;

    // Prologue: stage tile 0, drain, barrier.
    stage_tile(qbase, lds[0], tid);
    asm volatile("s_waitcnt vmcnt(0)" ::: "memory");
    __builtin_amdgcn_s_barrier();
    __builtin_amdgcn_sched_barrier(0);

    for (int t = 0; t < NT; ++t) {
        const int jbase = jq * JSPAN + t * BN;
        const char* cur = lds[t & 1];

        // Issue next tile's loads first: they fly under this tile's MFMAs.
        if (t + 1 < NT)
            stage_tile(qbase + (size_t)(t + 1) * BN * 512, lds[(t + 1) & 1], tid);

        // Special tiles: contain this wave's diagonal or pick columns.
        const bool special = (jbase <= i0w + RPW) && (jbase + BN > i0w);

#pragma unroll
        for (int cig = 0; cig < 2; ++cig) {
            f32x4 acc[4][2];
#pragma unroll
            for (int mi = 0; mi < 4; ++mi)
#pragma unroll
                for (int c2 = 0; c2 < 2; ++c2) acc[mi][c2] = f32x4{0.f, 0.f, 0.f, 0.f};

#pragma unroll
            for (int c2 = 0; c2 < 2; ++c2) {
                const int cl  = (cig * 2 + c2) * 16 + l15;
                const char* cb = cur + cl * 512;
                const int swz = (cl & 7) << 4;
                bf16x8 b[8];
#pragma unroll
                for (int kk = 0; kk < 8; ++kk)
                    b[kk] = *reinterpret_cast<const bf16x8*>(cb + ((kk * 64 + lks * 16) ^ swz));
#pragma unroll
                for (int kk = 0; kk < 8; ++kk)
#pragma unroll
                    for (int mi = 0; mi < 4; ++mi)
                        acc[mi][c2] = __builtin_amdgcn_mfma_f32_16x16x32_bf16(
                            a[mi][kk], b[kk], acc[mi][c2], 0, 0, 0);
            }

            // Epilogue. C/D layout: col = lane&15, row = (lane>>4)*4 + r.
            if (!special) {
#pragma unroll
                for (int mi = 0; mi < 4; ++mi)
#pragma unroll
                    for (int c2 = 0; c2 < 2; ++c2)
#pragma unroll
                        for (int r = 0; r < 4; ++r)
                            racc[mi][r] += __expf(-acc[mi][c2][r]);
            } else {
#pragma unroll
                for (int mi = 0; mi < 4; ++mi) {
                    const int ig0 = i0w + mi * 16 + lks * 4;
#pragma unroll
                    for (int c2 = 0; c2 < 2; ++c2) {
                        const int jg = jbase + (cig * 2 + c2) * 16 + l15;
#pragma unroll
                        for (int r = 0; r < 4; ++r) {
                            const float s  = acc[mi][c2][r];
                            const int   ig = ig0 + r;
                            racc[mi][r] += (jg == ig) ? 0.0f : __expf(-s);
                            const int pc = (ig == NROWS - 1) ? (NROWS - 2) : (ig + 1);
                            if (jg == pc) pickv[ig] = s;
                        }
                    }
                }
            }
        }

        // Drain this wave's prefetch, then barrier: next buffer is ready and
        // everyone is done reading the buffer we'll overwrite next iteration.
        asm volatile("s_waitcnt vmcnt(0)" ::: "memory");
        __builtin_amdgcn_s_barrier();
        __builtin_amdgcn_sched_barrier(0);
    }

    // Reduce row partials across the 16 col-lanes, one atomicAdd per row.
#pragma unroll
    for (int mi = 0; mi < 4; ++mi)
#pragma unroll
        for (int r = 0; r < 4; ++r) {
            float v = racc[mi][r];
            v += __shfl_xor(v, 1, 64);
            v += __shfl_xor(v, 2, 64);
            v += __shfl_xor(v, 4, 64);
            v += __shfl_xor(v, 8, 64);
            if (l15 == 0) atomicAdd(&rowsum[i0w + mi * 16 + lks * 4 + r], v);
        }
}

// ---------------- Kernel 3: deterministic final reduce ----------------
__global__ __launch_bounds__(256) void k_finalize(const float* __restrict__ rowsum,
                                                  const float* __restrict__ pickv,
                                                  float* __restrict__ out) {
    __shared__ float red[4];
    float s = 0.0f;
    for (int i = threadIdx.x; i < NROWS; i += 256) s += logf(rowsum[i]) + pickv[i];
#pragma unroll
    for (int m = 32; m >= 1; m >>= 1) s += __shfl_xor(s, m, 64);
    if ((threadIdx.x & 63) == 0) red[threadIdx.x >> 6] = s;
    __syncthreads();
    if (threadIdx.x == 0)
        out[0] = (red[0] + red[1] + red[2] + red[3]) * (1.0f / (float)NROWS);
}

extern "C" void kernel_launch(void* const* d_in, const int* in_sizes, int n_in,
                              void* d_out, int out_size, void* d_ws, size_t ws_size,
                              hipStream_t stream) {
    const float* emb = (const float*)d_in[0];
    const float* qry = (const float*)d_in[1];
    float* out = (float*)d_out;

    char* ws = (char*)d_ws;
    __hip_bfloat16* En = (__hip_bfloat16*)ws;                                  // 4 MB
    __hip_bfloat16* Qn = (__hip_bfloat16*)(ws + (size_t)NROWS * DIM * 2);      // 4 MB
    float* rowsum = (float*)(ws + (size_t)NROWS * DIM * 4);                    // 32 KB
    float* pickv  = rowsum + NROWS;                                            // 32 KB

    hipMemsetAsync(rowsum, 0, NROWS * sizeof(float), stream);
    k_normalize<<<NROWS / 4, 256, 0, stream>>>(emb, En);
    k_normalize<<<NROWS / 4, 256, 0, stream>>>(qry, Qn);
    k_simlse<<<32 * NSPLIT, 256, 0, stream>>>(En, Qn, rowsum, pickv);
    k_finalize<<<1, 256, 0, stream>>>(rowsum, pickv, out);
}

// Round 3
// 65.077 us; speedup vs baseline: 1.3033x; 1.1329x over previous
//
#include <hip/hip_runtime.h>
#include <hip/hip_bf16.h>

#define NROWS 8192
#define DIM 256
#define NSPLIT 16
#define JSPAN (NROWS / NSPLIT)   /* 512 cols per block */
#define BN 32
#define NT (JSPAN / BN)          /* 16 tiles per block */
#define RPW 64                   /* rows per wave (A stationary) */
#define RPB 256                  /* rows per block (4 waves) */
#define TILE_BYTES (BN * 512)    /* 16 KB */

typedef __bf16 bf16x8 __attribute__((ext_vector_type(8)));
typedef float f32x4 __attribute__((ext_vector_type(4)));

// ---------------- Kernel 1: L2-normalize rows of BOTH inputs, fp32 -> bf16 ----
__global__ __launch_bounds__(256) void k_normalize_all(const float* __restrict__ emb,
                                                       const float* __restrict__ qry,
                                                       __hip_bfloat16* __restrict__ En,
                                                       __hip_bfloat16* __restrict__ Qn) {
    const int gr   = blockIdx.x * 4 + (threadIdx.x >> 6);
    const int lane = threadIdx.x & 63;
    const float* in;
    __hip_bfloat16* out;
    int row;
    if (gr < NROWS) { in = emb; out = En; row = gr; }
    else            { in = qry; out = Qn; row = gr - NROWS; }
    const float4 v = reinterpret_cast<const float4*>(in + (size_t)row * DIM)[lane];
    float ss = v.x * v.x + v.y * v.y + v.z * v.z + v.w * v.w;
#pragma unroll
    for (int m = 32; m >= 1; m >>= 1) ss += __shfl_xor(ss, m, 64);
    const float inv = 1.0f / fmaxf(sqrtf(ss), 1e-8f);
    __hip_bfloat16 o[4];
    o[0] = __float2bfloat16(v.x * inv);
    o[1] = __float2bfloat16(v.y * inv);
    o[2] = __float2bfloat16(v.z * inv);
    o[3] = __float2bfloat16(v.w * inv);
    reinterpret_cast<ushort4*>(out + (size_t)row * DIM)[lane] = *reinterpret_cast<const ushort4*>(o);
}

// Stage half (g=0,1) of one BN x DIM bf16 tile (16 KB) into LDS, width-16 DMA.
// LDS dest linear; swizzle applied on SOURCE address (involution XOR), ds_read
// applies the same XOR (both-sides rule, G21).
__device__ __forceinline__ void stage_half(const char* __restrict__ gbase,
                                           char* lbase, int tid, int g) {
    const int wbase = tid & 192;
    const int lane  = tid & 63;
#pragma unroll
    for (int rr = 2 * g; rr < 2 * g + 2; ++rr) {
        const int id  = rr * 256 + wbase + lane;   // chunk 0..1023
        const int c   = id >> 5;                   // local col 0..31
        const int off = (id & 31) * 16;            // byte in col's 512B row
        const char* src = gbase + c * 512 + (off ^ ((c & 7) << 4));
        char* dst = lbase + (rr * 256 + wbase) * 16;   // wave-uniform base
        __builtin_amdgcn_global_load_lds(
            (const __attribute__((address_space(1))) void*)src,
            (__attribute__((address_space(3))) void*)dst, 16, 0, 0);
    }
}

// ---------------- Kernel 2: fused sim-GEMM + row sum of exp(-s) ----------------
// Grid: 32 i-blocks x 16 j-splits. Block = 4 waves; wave owns 64 stationary
// A-rows in registers; 4 waves share the LDS Q-tile. 4-deep LDS ring,
// stage 2 tiles ahead, counted vmcnt(4) at tile boundaries (T4).
__global__ __launch_bounds__(256, 2) void k_simlse(const __hip_bfloat16* __restrict__ En,
                                                   const __hip_bfloat16* __restrict__ Qn,
                                                   float* __restrict__ rowsum,
                                                   float* __restrict__ pickv) {
    __shared__ char lds[4][TILE_BYTES];   // 64 KB ring
    const int bx   = blockIdx.x;
    const int ib   = bx >> 4;
    const int jq   = bx & 15;
    const int tid  = threadIdx.x;
    const int lane = tid & 63;
    const int w    = tid >> 6;
    const int l15  = lane & 15;
    const int lks  = lane >> 4;          // k-segment 0..3
    const int i0w  = ib * RPB + w * RPW;

    // A fragments: 64 rows x K=256 -> a[4][8] (128 regs).
    bf16x8 a[4][8];
    {
        const __hip_bfloat16* ab = En + (size_t)(i0w + l15) * DIM + lks * 8;
#pragma unroll
        for (int mi = 0; mi < 4; ++mi)
#pragma unroll
            for (int kk = 0; kk < 8; ++kk)
                a[mi][kk] = *reinterpret_cast<const bf16x8*>(ab + mi * 16 * DIM + kk * 32);
    }

    float racc[4][4];
#pragma unroll
    for (int mi = 0; mi < 4; ++mi)
#pragma unroll
        for (int r = 0; r < 4; ++r) racc[mi][r] = 0.0f;

    const char* qbase = (const char*)Qn + (size_t)jq * JSPAN * 512;

    // Prologue: stage tiles 0 and 1; wait only for tile 0 (vmcnt(4) leaves
    // tile 1's 4 loads in flight).
    stage_half(qbase, lds[0], tid, 0);
    stage_half(qbase, lds[0], tid, 1);
    stage_half(qbase + TILE_BYTES, lds[1], tid, 0);
    stage_half(qbase + TILE_BYTES, lds[1], tid, 1);
    asm volatile("s_waitcnt vmcnt(4)" ::: "memory");
    __builtin_amdgcn_s_barrier();
    __builtin_amdgcn_sched_barrier(0);

    for (int t = 0; t < NT; ++t) {
        const char* cur    = lds[t & 3];
        const int jbase    = jq * JSPAN + t * BN;
        const bool spec    = (jbase <= i0w + RPW) && (jbase + BN > i0w);
        const char* nstage = qbase + (size_t)(t + 2) * TILE_BYTES;
        char* nbuf         = lds[(t + 2) & 3];

#pragma unroll
        for (int g = 0; g < 2; ++g) {
            // Phase g: ds_read this tile's 16-col group, issue 2 DMA loads for
            // tile t+2, MFMA under setprio, then exp epilogue (VALU) — phases
            // give the CU scheduler role diversity across waves (T5).
            const int cl   = g * 16 + l15;
            const char* cb = cur + cl * 512;
            const int swz  = (cl & 7) << 4;
            bf16x8 b[8];
#pragma unroll
            for (int kk = 0; kk < 8; ++kk)
                b[kk] = *reinterpret_cast<const bf16x8*>(cb + ((kk * 64 + lks * 16) ^ swz));

            if (t + 2 < NT) stage_half(nstage, nbuf, tid, g);

            f32x4 acc[4];
#pragma unroll
            for (int mi = 0; mi < 4; ++mi) acc[mi] = f32x4{0.f, 0.f, 0.f, 0.f};

            __builtin_amdgcn_s_setprio(1);
#pragma unroll
            for (int kk = 0; kk < 8; ++kk)
#pragma unroll
                for (int mi = 0; mi < 4; ++mi)
                    acc[mi] = __builtin_amdgcn_mfma_f32_16x16x32_bf16(
                        a[mi][kk], b[kk], acc[mi], 0, 0, 0);
            __builtin_amdgcn_s_setprio(0);

            // Epilogue. C/D layout: col = lane&15, row = (lane>>4)*4 + r.
            if (!spec) {
#pragma unroll
                for (int mi = 0; mi < 4; ++mi)
#pragma unroll
                    for (int r = 0; r < 4; ++r)
                        racc[mi][r] += __expf(-acc[mi][r]);
            } else {
                const int jg = jbase + g * 16 + l15;
#pragma unroll
                for (int mi = 0; mi < 4; ++mi) {
                    const int ig0 = i0w + mi * 16 + lks * 4;
#pragma unroll
                    for (int r = 0; r < 4; ++r) {
                        const float s  = acc[mi][r];
                        const int   ig = ig0 + r;
                        racc[mi][r] += (jg == ig) ? 0.0f : __expf(-s);
                        const int pc = (ig == NROWS - 1) ? (NROWS - 2) : (ig + 1);
                        if (jg == pc) pickv[ig] = s;
                    }
                }
            }
        }

        if (t < NT - 1) {
            // Counted wait: tile t+1's 4 loads must be done; tile t+2's 4 may
            // stay in flight. Only the last prefetch-less boundary drains.
            if (t + 2 < NT) asm volatile("s_waitcnt vmcnt(4)" ::: "memory");
            else            asm volatile("s_waitcnt vmcnt(0)" ::: "memory");
            __builtin_amdgcn_s_barrier();
            __builtin_amdgcn_sched_barrier(0);
        }
    }

    // Reduce row partials across the 16 col-lanes, one atomicAdd per row.
#pragma unroll
    for (int mi = 0; mi < 4; ++mi)
#pragma unroll
        for (int r = 0; r < 4; ++r) {
            float v = racc[mi][r];
            v += __shfl_xor(v, 1, 64);
            v += __shfl_xor(v, 2, 64);
            v += __shfl_xor(v, 4, 64);
            v += __shfl_xor(v, 8, 64);
            if (l15 == 0) atomicAdd(&rowsum[i0w + mi * 16 + lks * 4 + r], v);
        }
}

// ---------------- Kernel 3: deterministic final reduce ----------------
__global__ __launch_bounds__(256) void k_finalize(const float* __restrict__ rowsum,
                                                  const float* __restrict__ pickv,
                                                  float* __restrict__ out) {
    __shared__ float red[4];
    float s = 0.0f;
    for (int i = threadIdx.x; i < NROWS; i += 256) s += logf(rowsum[i]) + pickv[i];
#pragma unroll
    for (int m = 32; m >= 1; m >>= 1) s += __shfl_xor(s, m, 64);
    if ((threadIdx.x & 63) == 0) red[threadIdx.x >> 6] = s;
    __syncthreads();
    if (threadIdx.x == 0)
        out[0] = (red[0] + red[1] + red[2] + red[3]) * (1.0f / (float)NROWS);
}

extern "C" void kernel_launch(void* const* d_in, const int* in_sizes, int n_in,
                              void* d_out, int out_size, void* d_ws, size_t ws_size,
                              hipStream_t stream) {
    const float* emb = (const float*)d_in[0];
    const float* qry = (const float*)d_in[1];
    float* out = (float*)d_out;

    char* ws = (char*)d_ws;
    __hip_bfloat16* En = (__hip_bfloat16*)ws;                                  // 4 MB
    __hip_bfloat16* Qn = (__hip_bfloat16*)(ws + (size_t)NROWS * DIM * 2);      // 4 MB
    float* rowsum = (float*)(ws + (size_t)NROWS * DIM * 4);                    // 32 KB
    float* pickv  = rowsum + NROWS;                                            // 32 KB

    hipMemsetAsync(rowsum, 0, NROWS * sizeof(float), stream);
    k_normalize_all<<<2 * NROWS / 4, 256, 0, stream>>>(emb, qry, En, Qn);
    k_simlse<<<32 * NSPLIT, 256, 0, stream>>>(En, Qn, rowsum, pickv);
    k_finalize<<<1, 256, 0, stream>>>(rowsum, pickv, out);
}